// Round 7
// baseline (22.518 us; speedup 1.0000x reference)
//
#include <hip/hip_runtime.h>

#define KK 784      // 28*28 pixels per image
#define NE 5        // experts

typedef float fx4 __attribute__((ext_vector_type(4)));

__device__ __forceinline__ float dot4(fx4 a, fx4 b) {
    return a.x * b.x + a.y * b.y + a.z * b.z + a.w * b.w;
}

// One sample per FULL wave64, one shot. Every x load instruction is a single
// contiguous 1024B segment (no multi-row segment splitting at TA/L1).
// No LDS; weights (15.7 KB) served from L1. 32 waves/CU.
__global__ __launch_bounds__(256, 8) void moe_conv_fused_kernel(
    const float* __restrict__ x,        // [B, 784]
    const int*   __restrict__ cat,      // [B]
    const float* __restrict__ conv_w,   // [5, 784]
    const float* __restrict__ conv_b,   // [5]
    const float* __restrict__ fc1_w,    // [1, 5] -> 5 floats
    const float* __restrict__ fc1_b,    // [1]
    float*       __restrict__ out,      // [B]
    int B)
{
    const int tid  = blockIdx.x * blockDim.x + threadIdx.x;
    const int s    = tid >> 6;                 // one sample per wave
    const int lane = threadIdx.x & 63;
    if (s >= B) return;

    const int e = cat[s];                      // wave-uniform -> scalar broadcast
    const fx4* __restrict__ xv =
        reinterpret_cast<const fx4*>(x) + (size_t)s * (KK / 4);
    const fx4* __restrict__ wv =
        reinterpret_cast<const fx4*>(conv_w) + (size_t)e * (KK / 4);

    // 196 float4 over 64 lanes: 3 each + lanes 0..3 take #192+lane.
    // All x loads issued back-to-back; each is one contiguous 1KB wave segment.
    fx4 x0 = xv[lane];
    fx4 x1 = xv[lane + 64];
    fx4 x2 = xv[lane + 128];
    const bool extra = (lane < 4);
    fx4 xt;
    if (extra) xt = xv[192 + lane];

    fx4 w0 = wv[lane];
    fx4 w1 = wv[lane + 64];
    fx4 w2 = wv[lane + 128];

    float a0 = dot4(x0, w0);
    float a1 = dot4(x1, w1);
    float a2 = dot4(x2, w2);
    if (extra) {
        fx4 wt = wv[192 + lane];
        a0 += dot4(xt, wt);
    }
    float acc = a0 + a1 + a2;

    // full-wave reduce (6 steps)
    #pragma unroll
    for (int off = 32; off > 0; off >>= 1)
        acc += __shfl_down(acc, off, 64);

    if (lane == 0) {
        float o = (acc + conv_b[e]) * fc1_w[e] + fc1_b[0];
        out[s] = fmaxf(o, 0.0f);
    }
}

extern "C" void kernel_launch(void* const* d_in, const int* in_sizes, int n_in,
                              void* d_out, int out_size, void* d_ws, size_t ws_size,
                              hipStream_t stream) {
    const float* x      = (const float*)d_in[0];
    const int*   cat    = (const int*)d_in[1];
    const float* conv_w = (const float*)d_in[2];
    const float* conv_b = (const float*)d_in[3];
    const float* fc1_w  = (const float*)d_in[4];
    const float* fc1_b  = (const float*)d_in[5];
    float* out = (float*)d_out;

    const int B = in_sizes[1];          // category_indices element count
    (void)d_ws; (void)ws_size; (void)n_in; (void)out_size;

    const int block = 256;              // 4 waves/block, 4 samples/block
    const int grid  = (B + 3) / 4;      // B=32768 -> 8192 blocks

    moe_conv_fused_kernel<<<grid, block, 0, stream>>>(
        x, cat, conv_w, conv_b, fc1_w, fc1_b, out, B);
}

// Round 8
// 20.614 us; speedup vs baseline: 1.0924x; 1.0924x over previous
//
#include <hip/hip_runtime.h>

#define KK 784      // 28*28 pixels per image
#define NE 5        // experts

typedef float fx4 __attribute__((ext_vector_type(4)));

__device__ __forceinline__ float dot4(fx4 a, fx4 b) {
    return a.x * b.x + a.y * b.y + a.z * b.z + a.w * b.w;
}

// Best-measured variant (R4, 20.7 us): one wave = 2 adjacent samples, one
// 32-lane group per sample, single pass. No LDS (weights L1-resident),
// low VGPR -> __launch_bounds__(256,8) = 32 waves/CU.
// Falsified levers: LDS staging (22.8), NT bypass (22.0), 1-sample/wave
// single-segment loads (22.5), 16 waves/CU (20.9) -- all flat or worse.
__global__ __launch_bounds__(256, 8) void moe_conv_fused_kernel(
    const float* __restrict__ x,        // [B, 784]
    const int*   __restrict__ cat,      // [B]
    const float* __restrict__ conv_w,   // [5, 784]
    const float* __restrict__ conv_b,   // [5]
    const float* __restrict__ fc1_w,    // [1, 5] -> 5 floats
    const float* __restrict__ fc1_b,    // [1]
    float*       __restrict__ out,      // [B]
    int B)
{
    const int tid  = blockIdx.x * blockDim.x + threadIdx.x;
    const int wid  = tid >> 6;                 // global wave id
    const int lane = threadIdx.x & 63;
    const int grp  = lane >> 5;                // 0..1 : sample within wave
    const int sub  = lane & 31;                // lane within 32-lane group
    const int s    = wid * 2 + grp;            // sample id (one shot, no loop)
    if (s >= B) return;

    const int e = cat[s];                      // uniform per 32-lane group
    const fx4* __restrict__ xv =
        reinterpret_cast<const fx4*>(x) + (size_t)s * (KK / 4);
    const fx4* __restrict__ wv =
        reinterpret_cast<const fx4*>(conv_w) + (size_t)e * (KK / 4);

    // 196 float4 per sample over 32 lanes: 6 each + lanes 0..3 take #192+sub
    fx4 xa[6];
    #pragma unroll
    for (int i = 0; i < 6; ++i)
        xa[i] = xv[sub + 32 * i];              // independent, issue back-to-back

    const bool extra = (sub < 4);
    fx4 xt;
    if (extra) xt = xv[192 + sub];

    // weights stream from L1; 3 accumulators break the FMA chain
    float a0, a1, a2;
    {
        fx4 w0 = wv[sub];
        fx4 w1 = wv[sub + 32];
        fx4 w2 = wv[sub + 64];
        a0 = dot4(xa[0], w0);
        a1 = dot4(xa[1], w1);
        a2 = dot4(xa[2], w2);
    }
    {
        fx4 w0 = wv[sub + 96];
        fx4 w1 = wv[sub + 128];
        fx4 w2 = wv[sub + 160];
        a0 += dot4(xa[3], w0);
        a1 += dot4(xa[4], w1);
        a2 += dot4(xa[5], w2);
    }
    if (extra) {
        fx4 wt = wv[192 + sub];
        a0 += dot4(xt, wt);
    }
    float acc = a0 + a1 + a2;

    // reduce within each 32-lane group (2 samples reduced simultaneously)
    #pragma unroll
    for (int off = 16; off > 0; off >>= 1)
        acc += __shfl_down(acc, off, 32);

    if (sub == 0) {
        float o = (acc + conv_b[e]) * fc1_w[e] + fc1_b[0];
        out[s] = fmaxf(o, 0.0f);               // lanes 0,32 -> adjacent floats
    }
}

extern "C" void kernel_launch(void* const* d_in, const int* in_sizes, int n_in,
                              void* d_out, int out_size, void* d_ws, size_t ws_size,
                              hipStream_t stream) {
    const float* x      = (const float*)d_in[0];
    const int*   cat    = (const int*)d_in[1];
    const float* conv_w = (const float*)d_in[2];
    const float* conv_b = (const float*)d_in[3];
    const float* fc1_w  = (const float*)d_in[4];
    const float* fc1_b  = (const float*)d_in[5];
    float* out = (float*)d_out;

    const int B = in_sizes[1];          // category_indices element count
    (void)d_ws; (void)ws_size; (void)n_in; (void)out_size;

    const int block = 256;              // 4 waves/block, 8 samples/block
    const int grid  = (B + 7) / 8;      // B=32768 -> 4096 blocks

    moe_conv_fused_kernel<<<grid, block, 0, stream>>>(
        x, cat, conv_w, conv_b, fc1_w, fc1_b, out, B);
}